// Round 2
// baseline (460.321 us; speedup 1.0000x reference)
//
#include <hip/hip_runtime.h>

#define NN 100000
#define NE 1600000
#define NB 256   // dst buckets
#define BSZ 391  // nodes per bucket (255*391=99705; bucket 255 holds 295)
#define EB 782   // edge blocks of 2048 (782*2048 >= NE)

typedef __attribute__((ext_vector_type(8))) short short8;
typedef __attribute__((ext_vector_type(4))) float floatx4;

__device__ __forceinline__ unsigned short f2bf(float f) {
  unsigned u = __float_as_uint(f);
  u += 0x7fffu + ((u >> 16) & 1u);  // RNE
  return (unsigned short)(u >> 16);
}
__device__ __forceinline__ float bf2f(unsigned short b) {
  return __uint_as_float(((unsigned)b) << 16);
}

// ---------------------------------------------------------------------------
// Convert the 4 weight matrices (each 64x64 f32 row-major) to bf16.
__global__ __launch_bounds__(256) void k_cvtW(const float* __restrict__ W1,
                                              const float* __restrict__ W2,
                                              const float* __restrict__ W3,
                                              const float* __restrict__ W4,
                                              unsigned short* __restrict__ Wb) {
  int i = blockIdx.x * 256 + threadIdx.x;  // 16 blocks * 256 = 4096 exact
  Wb[i] = f2bf(W1[i]);
  Wb[4096 + i] = f2bf(W2[i]);
  Wb[8192 + i] = f2bf(W3[i]);
  Wb[12288 + i] = f2bf(W4[i]);
}

// ---------------------------------------------------------------------------
// ELL build via bucket partition — NO global atomics (only LDS).
// Pass 1: per-(block,bucket) histogram.
__global__ __launch_bounds__(256) void k_phist(const int* __restrict__ dst,
                                               int* __restrict__ blockHist) {
  __shared__ int h[NB];
  h[threadIdx.x] = 0;
  __syncthreads();
  int base = blockIdx.x * 2048;
#pragma unroll
  for (int i = 0; i < 8; i++) {
    int e = base + i * 256 + threadIdx.x;
    if (e < NE) atomicAdd(&h[dst[e] / BSZ], 1);
  }
  __syncthreads();
  blockHist[blockIdx.x * NB + threadIdx.x] = h[threadIdx.x];
}

// Pass 2: per-bucket exclusive scan over the EB block counts.
__global__ __launch_bounds__(1024) void k_colscan(const int* __restrict__ blockHist,
                                                  int* __restrict__ offsL,
                                                  int* __restrict__ colTot) {
  __shared__ int sh[1024];
  int c = blockIdx.x, t = threadIdx.x;
  int v = (t < EB) ? blockHist[t * NB + c] : 0;
  sh[t] = v;
  __syncthreads();
  for (int off = 1; off < 1024; off <<= 1) {
    int u = (t >= off) ? sh[t - off] : 0;
    __syncthreads();
    sh[t] += u;
    __syncthreads();
  }
  if (t < EB) offsL[t * NB + c] = sh[t] - v;  // exclusive within column
  if (t == EB - 1) colTot[c] = sh[t];
}

// Pass 3: exclusive scan of the 256 bucket totals -> bucket bases.
__global__ __launch_bounds__(256) void k_basescan(const int* __restrict__ colTot,
                                                  int* __restrict__ base) {
  __shared__ int sh[256];
  int t = threadIdx.x;
  int v = colTot[t];
  sh[t] = v;
  __syncthreads();
  for (int off = 1; off < 256; off <<= 1) {
    int u = (t >= off) ? sh[t - off] : 0;
    __syncthreads();
    sh[t] += u;
    __syncthreads();
  }
  base[t] = sh[t] - v;
  if (t == 255) base[256] = sh[255];
}

// Pass 4: scatter (src,dst) into bucket-partitioned array; rank via LDS atomic.
__global__ __launch_bounds__(256) void k_escat(const int* __restrict__ src,
                                               const int* __restrict__ dst,
                                               const int* __restrict__ offsL,
                                               const int* __restrict__ base,
                                               int2* __restrict__ ed) {
  __shared__ int h[NB];
  h[threadIdx.x] = 0;
  __syncthreads();
  int eb = blockIdx.x * 2048;
  const int* ofs = offsL + blockIdx.x * NB;
#pragma unroll
  for (int i = 0; i < 8; i++) {
    int e = eb + i * 256 + threadIdx.x;
    if (e < NE) {
      int d = dst[e];
      int c = d / BSZ;
      int r = atomicAdd(&h[c], 1);
      ed[base[c] + ofs[c] + r] = make_int2(src[e], d);
    }
  }
}

// Pass 5: one block per bucket; LDS cursors assign ELL slots; emit deg[].
// ELL is stored TRANSPOSED: ellT[slot][node] so the gather streams it
// coalesced (256 B per wave per slot step).
__global__ __launch_bounds__(256) void k_ellfill(const int2* __restrict__ ed,
                                                 const int* __restrict__ base,
                                                 int* __restrict__ ellT,
                                                 int* __restrict__ deg) {
  __shared__ int cur[BSZ];
  int c = blockIdx.x;
  for (int i = threadIdx.x; i < BSZ; i += 256) cur[i] = 0;
  __syncthreads();
  int lo = base[c], hi = base[c + 1];
  int n0 = c * BSZ;
  for (int e = lo + threadIdx.x; e < hi; e += 256) {
    int2 sd = ed[e];
    int slot = atomicAdd(&cur[sd.y - n0], 1);
    if (slot < 64) ellT[(size_t)slot * NN + sd.y] = sd.x;
  }
  __syncthreads();
  for (int i = threadIdx.x; i < BSZ; i += 256) {
    int n = n0 + i;
    if (n < NN) deg[n] = min(cur[i], 64);
  }
}

// ---------------------------------------------------------------------------
// Transpose x (f32 [NN][64] row-major) into slice-major xs [8][NN][8].
// Block = 32 nodes x 8 slices. Reads 2 KB contiguous per wave; NT stores
// (the slice only needs to be in L3 — each XCD pulls its own slice on first
// gather touch).
__global__ __launch_bounds__(256) void k_xpose(const float* __restrict__ x,
                                               float* __restrict__ xs) {
  int nl = threadIdx.x >> 3, s = threadIdx.x & 7;
  int n = blockIdx.x * 32 + nl;  // 3125 blocks * 32 = NN exact
  const floatx4* rp = (const floatx4*)(x + (size_t)n * 64 + s * 8);
  floatx4 v0 = rp[0], v1 = rp[1];
  floatx4* wp = (floatx4*)(xs + ((size_t)s * NN + n) * 8);
  __builtin_nontemporal_store(v0, wp);
  __builtin_nontemporal_store(v1, wp + 1);
}

// ---------------------------------------------------------------------------
// XCD-pinned sliced gather.
// agg[n] = (1+eps) * pre(x[n]) + sum_{s in N(n)} pre(x[s]); output bf16
// slice-major [8][NN][8].
// Block b handles feature slice (b&7) for node chunk (b>>3)*256.. — with the
// hardware's round-robin blockIdx->XCD mapping, XCD x only touches slice x
// (1.6 MB bf16 / 3.2 MB f32), which is resident in its 4 MB L2. Neighbor
// reads become L2 hits instead of random 128B-line misses at the ~24 G
// lines/s L3/HBM service ceiling.
// MODE 0: f32 slice input (xs), pre=identity.
// MODE 1: bf16 slice input (xb), pre=BN1 affine, factored out of the loop:
//   agg = A*(es*v_n + sum v_s) + B*(es + deg).
template <int MODE>
__global__ __launch_bounds__(256) void k_gather(const float* __restrict__ xs,
                                                const unsigned short* __restrict__ xb,
                                                const int* __restrict__ deg,
                                                const int* __restrict__ ellT,
                                                const float* __restrict__ eps,
                                                const float* __restrict__ AB,
                                                unsigned short* __restrict__ agg) {
  const int s = blockIdx.x & 7;                       // feature slice == XCD
  const int n = (blockIdx.x >> 3) * 256 + (int)threadIdx.x;
  if (n >= NN) return;
  const float es = 1.0f + eps[0];
  const int cnt = __builtin_nontemporal_load(deg + n);
  const size_t sbase = (size_t)s * NN;

  float a0[8], a1[8];
#pragma unroll
  for (int i = 0; i < 8; i++) a1[i] = 0.0f;

  if (MODE) {
    short8 v = *(const short8*)(xb + (sbase + n) * 8);
#pragma unroll
    for (int i = 0; i < 8; i++) a0[i] = es * bf2f((unsigned short)v[i]);
  } else {
    const floatx4* sp = (const floatx4*)(xs + (sbase + n) * 8);
    floatx4 v0 = sp[0], v1 = sp[1];
    a0[0] = es * v0.x; a0[1] = es * v0.y; a0[2] = es * v0.z; a0[3] = es * v0.w;
    a0[4] = es * v1.x; a0[5] = es * v1.y; a0[6] = es * v1.z; a0[7] = es * v1.w;
  }

  const int* ep = ellT + n;  // ellT[j][n]: coalesced stream across lanes
  int j = 0;
  for (; j + 4 <= cnt; j += 4) {
    int i0 = __builtin_nontemporal_load(ep + (size_t)(j + 0) * NN);
    int i1 = __builtin_nontemporal_load(ep + (size_t)(j + 1) * NN);
    int i2 = __builtin_nontemporal_load(ep + (size_t)(j + 2) * NN);
    int i3 = __builtin_nontemporal_load(ep + (size_t)(j + 3) * NN);
    if (MODE) {
      short8 u0 = *(const short8*)(xb + (sbase + i0) * 8);
      short8 u1 = *(const short8*)(xb + (sbase + i1) * 8);
      short8 u2 = *(const short8*)(xb + (sbase + i2) * 8);
      short8 u3 = *(const short8*)(xb + (sbase + i3) * 8);
#pragma unroll
      for (int i = 0; i < 8; i++) {
        a0[i] += bf2f((unsigned short)u0[i]) + bf2f((unsigned short)u1[i]);
        a1[i] += bf2f((unsigned short)u2[i]) + bf2f((unsigned short)u3[i]);
      }
    } else {
      const floatx4* p0 = (const floatx4*)(xs + (sbase + i0) * 8);
      const floatx4* p1 = (const floatx4*)(xs + (sbase + i1) * 8);
      const floatx4* p2 = (const floatx4*)(xs + (sbase + i2) * 8);
      const floatx4* p3 = (const floatx4*)(xs + (sbase + i3) * 8);
      floatx4 q00 = p0[0], q01 = p0[1], q10 = p1[0], q11 = p1[1];
      floatx4 q20 = p2[0], q21 = p2[1], q30 = p3[0], q31 = p3[1];
      a0[0] += q00.x + q10.x; a0[1] += q00.y + q10.y;
      a0[2] += q00.z + q10.z; a0[3] += q00.w + q10.w;
      a0[4] += q01.x + q11.x; a0[5] += q01.y + q11.y;
      a0[6] += q01.z + q11.z; a0[7] += q01.w + q11.w;
      a1[0] += q20.x + q30.x; a1[1] += q20.y + q30.y;
      a1[2] += q20.z + q30.z; a1[3] += q20.w + q30.w;
      a1[4] += q21.x + q31.x; a1[5] += q21.y + q31.y;
      a1[6] += q21.z + q31.z; a1[7] += q21.w + q31.w;
    }
  }
  for (; j < cnt; j++) {
    int i0 = __builtin_nontemporal_load(ep + (size_t)j * NN);
    if (MODE) {
      short8 u0 = *(const short8*)(xb + (sbase + i0) * 8);
#pragma unroll
      for (int i = 0; i < 8; i++) a0[i] += bf2f((unsigned short)u0[i]);
    } else {
      const floatx4* p0 = (const floatx4*)(xs + (sbase + i0) * 8);
      floatx4 t0 = p0[0], t1 = p0[1];
      a0[0] += t0.x; a0[1] += t0.y; a0[2] += t0.z; a0[3] += t0.w;
      a0[4] += t1.x; a0[5] += t1.y; a0[6] += t1.z; a0[7] += t1.w;
    }
  }

  float r[8];
  if (MODE) {
    const floatx4* Ap = (const floatx4*)(AB + s * 8);
    const floatx4* Bp = (const floatx4*)(AB + 64 + s * 8);
    floatx4 Aa = Ap[0], Ab = Ap[1], Ba = Bp[0], Bb = Bp[1];
    float w = es + (float)cnt;
    r[0] = fmaf(a0[0] + a1[0], Aa.x, w * Ba.x);
    r[1] = fmaf(a0[1] + a1[1], Aa.y, w * Ba.y);
    r[2] = fmaf(a0[2] + a1[2], Aa.z, w * Ba.z);
    r[3] = fmaf(a0[3] + a1[3], Aa.w, w * Ba.w);
    r[4] = fmaf(a0[4] + a1[4], Ab.x, w * Bb.x);
    r[5] = fmaf(a0[5] + a1[5], Ab.y, w * Bb.y);
    r[6] = fmaf(a0[6] + a1[6], Ab.z, w * Bb.z);
    r[7] = fmaf(a0[7] + a1[7], Ab.w, w * Bb.w);
  } else {
#pragma unroll
    for (int i = 0; i < 8; i++) r[i] = a0[i] + a1[i];
  }
  short8 st;
#pragma unroll
  for (int i = 0; i < 8; i++) st[i] = (short)f2bf(r[i]);
  __builtin_nontemporal_store(st, (short8*)(agg + (sbase + n) * 8));
}

// ---------------------------------------------------------------------------
// h2 = relu(relu(agg@Wa+ba)@Wb+bb) via bf16 MFMA 16x16x32; BN stats to f64.
// agg and h2 are slice-major [8][NN][8].
__global__ __launch_bounds__(256) void k_mlp_mfma(
    const unsigned short* __restrict__ agg, const unsigned short* __restrict__ Wab,
    const float* __restrict__ ba, const float* __restrict__ bb,
    unsigned short* __restrict__ h2, double* __restrict__ stats) {
  const int l = threadIdx.x & 63;
  const int wv = threadIdx.x >> 6;
  const int l16 = l & 15, quad = l >> 4;

  short8 wfa[4][2], wfb[4][2];
#pragma unroll
  for (int c = 0; c < 4; c++)
#pragma unroll
    for (int t = 0; t < 2; t++)
#pragma unroll
      for (int j = 0; j < 8; j++) {
        int k = t * 32 + quad * 8 + j, nn = c * 16 + l16;
        wfa[c][t][j] = (short)Wab[k * 64 + nn];
        wfb[c][t][j] = (short)Wab[4096 + k * 64 + nn];
      }
  float bia[4], bib[4];
#pragma unroll
  for (int c = 0; c < 4; c++) { bia[c] = ba[c * 16 + l16]; bib[c] = bb[c * 16 + l16]; }

  __shared__ float Hs[4][16][68];
  __shared__ float sS[4][64], sQ[4][64];
  float ssum[4] = {0, 0, 0, 0}, ssq[4] = {0, 0, 0, 0};

  const int totw = gridDim.x * 4;
  for (int tile = blockIdx.x * 4 + wv; tile < NN / 16; tile += totw) {
    const int r0 = tile * 16;
    // slice-major agg: feats quad*8..+8 live in slice quad; 32+quad*8 in 4+quad
    short8 a0 = *(const short8*)(agg + ((size_t)quad * NN + r0 + l16) * 8);
    short8 a1 = *(const short8*)(agg + ((size_t)(4 + quad) * NN + r0 + l16) * 8);
#pragma unroll
    for (int c = 0; c < 4; c++) {
      floatx4 acc = {0.f, 0.f, 0.f, 0.f};
      acc = __builtin_amdgcn_mfma_f32_16x16x32_bf16(a0, wfa[c][0], acc, 0, 0, 0);
      acc = __builtin_amdgcn_mfma_f32_16x16x32_bf16(a1, wfa[c][1], acc, 0, 0, 0);
#pragma unroll
      for (int r = 0; r < 4; r++)
        Hs[wv][quad * 4 + r][c * 16 + l16] = fmaxf(acc[r] + bia[c], 0.0f);
    }
    short8 a20, a21;
#pragma unroll
    for (int j = 0; j < 8; j++) {
      a20[j] = (short)f2bf(Hs[wv][l16][quad * 8 + j]);
      a21[j] = (short)f2bf(Hs[wv][l16][32 + quad * 8 + j]);
    }
#pragma unroll
    for (int c = 0; c < 4; c++) {
      floatx4 acc = {0.f, 0.f, 0.f, 0.f};
      acc = __builtin_amdgcn_mfma_f32_16x16x32_bf16(a20, wfb[c][0], acc, 0, 0, 0);
      acc = __builtin_amdgcn_mfma_f32_16x16x32_bf16(a21, wfb[c][1], acc, 0, 0, 0);
      int s2 = c * 2 + (l16 >> 3);  // output slice for feat c*16+l16
#pragma unroll
      for (int r = 0; r < 4; r++) {
        float v = fmaxf(acc[r] + bib[c], 0.0f);
        h2[((size_t)s2 * NN + (r0 + quad * 4 + r)) * 8 + (l16 & 7)] = f2bf(v);
        ssum[c] += v;
        ssq[c] += v * v;
      }
    }
  }
#pragma unroll
  for (int c = 0; c < 4; c++) {
    float s = ssum[c], q = ssq[c];
    s += __shfl_xor(s, 16, 64); s += __shfl_xor(s, 32, 64);
    q += __shfl_xor(q, 16, 64); q += __shfl_xor(q, 32, 64);
    if (quad == 0) { sS[wv][c * 16 + l16] = s; sQ[wv][c * 16 + l16] = q; }
  }
  __syncthreads();
  if (threadIdx.x < 64) {
    int ff = threadIdx.x;
    float s = sS[0][ff] + sS[1][ff] + sS[2][ff] + sS[3][ff];
    float q = sQ[0][ff] + sQ[1][ff] + sQ[2][ff] + sQ[3][ff];
    unsafeAtomicAdd(&stats[ff], (double)s);
    unsafeAtomicAdd(&stats[64 + ff], (double)q);
  }
}

// ---------------------------------------------------------------------------
// stats -> per-feature affine A (scale), B (shift): out = h*A + B
__global__ void k_bnfin(const double* __restrict__ stats, const float* __restrict__ gam,
                        const float* __restrict__ bet, float* __restrict__ AB) {
  int f = threadIdx.x;  // 64 threads
  double mean = stats[f] * (1.0 / NN);
  double var = stats[64 + f] * (1.0 / NN) - mean * mean;
  if (var < 0.0) var = 0.0;
  float rstd = (float)(1.0 / sqrt(var + 1e-5));
  float A = gam[f] * rstd;
  float B = bet[f] - (float)mean * A;
  AB[f] = A;
  AB[64 + f] = B;
}

// ---------------------------------------------------------------------------
// h = BN2(h2); out[0:N*64] = h; out[N*64:] = log_softmax(h) per row.
// h2 is slice-major [8][NN][8].
__global__ __launch_bounds__(256) void k_out(const unsigned short* __restrict__ h2,
                                             const float* __restrict__ AB,
                                             float* __restrict__ out) {
  int f = threadIdx.x & 63;
  int n = blockIdx.x * 4 + (threadIdx.x >> 6);  // 25000*4 = NN exact
  float v = bf2f(h2[((size_t)(f >> 3) * NN + n) * 8 + (f & 7)]);
  float h = fmaf(v, AB[f], AB[64 + f]);
  float m = h;
#pragma unroll
  for (int off = 32; off; off >>= 1) m = fmaxf(m, __shfl_xor(m, off, 64));
  float e = expf(h - m);
  float ssum = e;
#pragma unroll
  for (int off = 32; off; off >>= 1) ssum += __shfl_xor(ssum, off, 64);
  float lsm = (h - m) - logf(ssum);
  out[n * 64 + f] = h;
  out[(size_t)NN * 64 + n * 64 + f] = lsm;
}

// ---------------------------------------------------------------------------
extern "C" void kernel_launch(void* const* d_in, const int* in_sizes, int n_in,
                              void* d_out, int out_size, void* d_ws, size_t ws_size,
                              hipStream_t stream) {
  const float* x = (const float*)d_in[0];
  const int* ei = (const int*)d_in[1];  // [2, E] as int32
  const float* W1 = (const float*)d_in[2];
  const float* b1 = (const float*)d_in[3];
  const float* W2 = (const float*)d_in[4];
  const float* b2 = (const float*)d_in[5];
  const float* g1 = (const float*)d_in[6];
  const float* bt1 = (const float*)d_in[7];
  const float* e1 = (const float*)d_in[8];
  const float* W3 = (const float*)d_in[9];
  const float* b3 = (const float*)d_in[10];
  const float* W4 = (const float*)d_in[11];
  const float* b4 = (const float*)d_in[12];
  const float* g2 = (const float*)d_in[13];
  const float* bt2 = (const float*)d_in[14];
  const float* e2 = (const float*)d_in[15];
  const int* src = ei;
  const int* dst = ei + NE;

  char* ws = (char*)d_ws;
  // Layout (66.04 MB total, xs aliases h2b+ed which are dead at xpose time):
  unsigned short* aggb = (unsigned short*)(ws);            // [8][NN][8] bf16, 12.8 MB
  int* ellT = (int*)(ws + 12800000);                       // [64][NN] int, 25.6 MB
  unsigned short* h2b = (unsigned short*)(ws + 38400000);  // [8][NN][8] bf16, 12.8 MB
  float* xs = (float*)(ws + 38400000);                     // alias over h2b+ed, 25.6 MB
  int2* ed = (int2*)(ws + 51200000);                       // 12.8 MB partitioned edges
  int* blockHist = (int*)(ws + 64000000);                  // 782*256 ints
  int* offsL = (int*)(ws + 64800768);                      // 782*256 ints
  int* colTot = (int*)(ws + 65601536);                     // 256 ints
  int* base = (int*)(ws + 65602560);                       // 257 ints (pad to 1040)
  int* deg = (int*)(ws + 65603600);                        // 100000 ints
  double* st1 = (double*)(ws + 66003600);                  // 128 f64
  double* st2 = (double*)(ws + 66004624);                  // 128 f64
  float* AB1 = (float*)(ws + 66005648);                    // 128 f32
  float* AB2 = (float*)(ws + 66006160);                    // 128 f32
  unsigned short* Wbb = (unsigned short*)(ws + 66006672);  // 4*4096 bf16
  float* out = (float*)d_out;

  hipMemsetAsync(ws + 66003600, 0, 2048, stream);  // zero st1+st2

  k_cvtW<<<16, 256, 0, stream>>>(W1, W2, W3, W4, Wbb);

  // --- ELL build via bucket partition (no global atomics) ---
  k_phist<<<EB, 256, 0, stream>>>(dst, blockHist);
  k_colscan<<<NB, 1024, 0, stream>>>(blockHist, offsL, colTot);
  k_basescan<<<1, 256, 0, stream>>>(colTot, base);
  k_escat<<<EB, 256, 0, stream>>>(src, dst, offsL, base, ed);
  k_ellfill<<<NB, 256, 0, stream>>>(ed, base, ellT, deg);

  // --- x -> slice-major (ed is dead now; xs aliases h2b+ed) ---
  k_xpose<<<NN / 32, 256, 0, stream>>>(x, xs);

  // --- Layer 1 ---
  k_gather<0><<<8 * 391, 256, 0, stream>>>(xs, nullptr, deg, ellT, e1, nullptr, aggb);
  k_mlp_mfma<<<782, 256, 0, stream>>>(aggb, Wbb, b1, b2, h2b, st1);
  k_bnfin<<<1, 64, 0, stream>>>(st1, g1, bt1, AB1);
  // --- Layer 2 (BN1-apply fused into the gather, factored out of the loop) ---
  k_gather<1><<<8 * 391, 256, 0, stream>>>(nullptr, h2b, deg, ellT, e2, AB1, aggb);
  k_mlp_mfma<<<782, 256, 0, stream>>>(aggb, Wbb + 8192, b3, b4, h2b, st2);
  k_bnfin<<<1, 64, 0, stream>>>(st2, g2, bt2, AB2);
  // --- Epilogue: BN2 + log_softmax ---
  k_out<<<NN / 4, 256, 0, stream>>>(h2b, AB2, out);
}